// Round 6
// baseline (3428.518 us; speedup 1.0000x reference)
//
#include <hip/hip_runtime.h>

#define NN 16384
#define DD 16
#define KK 64
#define QQ 2            // queries per block (share x_j loads)
#define TPB 1024
#define HALF 512        // threads per query-half (8 waves)
#define CAND_MAX 512

// XLA:CPU vectorized row-reduce, minor dim 16: lane halving tree. (VALIDATED r5)
__device__ __forceinline__ float halving_sumsq16(const float* v) {
    float p[16];
#pragma unroll
    for (int d = 0; d < 16; ++d) p[d] = __fmul_rn(v[d], v[d]);
    float r8[8];
#pragma unroll
    for (int j = 0; j < 8; ++j) r8[j] = __fadd_rn(p[j], p[j + 8]);
    float r4[4];
#pragma unroll
    for (int j = 0; j < 4; ++j) r4[j] = __fadd_rn(r8[j], r8[j + 4]);
    float r2[2];
#pragma unroll
    for (int j = 0; j < 2; ++j) r2[j] = __fadd_rn(r4[j], r4[j + 2]);
    return __fadd_rn(r2[0], r2[1]);
}

// ---------------- prep: f32 squared norms (halving tree) + copy x ----------------
__global__ void prep_kernel(const float* __restrict__ x,
                            float* __restrict__ out_x,
                            float* __restrict__ sqf) {
    int i = blockIdx.x * blockDim.x + threadIdx.x;
    if (i < NN) {
        float v[DD];
#pragma unroll
        for (int d = 0; d < DD; ++d) v[d] = x[i * DD + d];
        sqf[i] = halving_sumsq16(v);
    }
    for (int t = i; t < NN * DD; t += gridDim.x * blockDim.x) {
        out_x[t] = x[t];
    }
}

// ---------------- main: 2 queries/block, exact top-K ----------------
__global__ __launch_bounds__(TPB, 4) void knn_kernel(
        const float* __restrict__ x,
        const int* __restrict__ pid,
        const float* __restrict__ sqf,
        float* __restrict__ out_src,
        float* __restrict__ out_dst,
        float* __restrict__ out_y,
        float* __restrict__ out_ef,
        float* __restrict__ out_mask) {
    __shared__ unsigned int keys[QQ][NN];            // 128 KB
    __shared__ unsigned int hist[QQ][256];
    __shared__ int cand_idx[QQ][CAND_MAX];
    __shared__ unsigned int cand_key[QQ][CAND_MAX];
    __shared__ float xi_s[QQ][DD];
    __shared__ unsigned int s_pref[QQ], s_need[QQ], s_cnt[QQ];

    const int bid = blockIdx.x;
    const int tid = threadIdx.x;
    const int h = tid >> 9;              // which query this thread serves (phases 2+)
    const int l = tid & (HALF - 1);      // index within half
    const int iA = bid * QQ;
    const int iB = iA + 1;
    const int iq = iA + h;

    if (tid < QQ * DD)
        xi_s[tid >> 4][tid & 15] = x[(iA + (tid >> 4)) * DD + (tid & 15)];
    if (tid < QQ) s_cnt[tid] = 0;
    __syncthreads();

    float xA[DD], xB[DD];
#pragma unroll
    for (int d = 0; d < DD; ++d) { xA[d] = xi_s[0][d]; xB[d] = xi_s[1][d]; }
    const float sqA = sqf[iA];
    const float sqB = sqf[iB];

    // ---- phase 1: shared x_j loads feed BOTH queries' d2 ----
    // d2 = f32( f32(sq_i + sq_j) - 2*dot ), dot = ascending-k fused-FMA (VALIDATED r5)
    for (int j = tid; j < NN; j += TPB) {
        const float4* xj4 = reinterpret_cast<const float4*>(x + j * DD);
        float4 a0 = xj4[0], a1 = xj4[1], a2 = xj4[2], a3 = xj4[3];
        float xj[DD] = {a0.x, a0.y, a0.z, a0.w, a1.x, a1.y, a1.z, a1.w,
                        a2.x, a2.y, a2.z, a2.w, a3.x, a3.y, a3.z, a3.w};
        float dotA = 0.0f, dotB = 0.0f;
#pragma unroll
        for (int d = 0; d < DD; ++d) {
            dotA = fmaf(xA[d], xj[d], dotA);
            dotB = fmaf(xB[d], xj[d], dotB);
        }
        const float sj = sqf[j];
        float d2A = __fsub_rn(__fadd_rn(sqA, sj), __fmul_rn(2.0f, dotA));
        float d2B = __fsub_rn(__fadd_rn(sqB, sj), __fmul_rn(2.0f, dotB));
        unsigned int uA = __float_as_uint(d2A);
        uA ^= (uA & 0x80000000u) ? 0xFFFFFFFFu : 0x80000000u;
        unsigned int uB = __float_as_uint(d2B);
        uB ^= (uB & 0x80000000u) ? 0xFFFFFFFFu : 0x80000000u;
        if (j == iA) uA = 0xFFFFFFFFu;
        if (j == iB) uB = 0xFFFFFFFFu;
        keys[0][j] = uA;
        keys[1][j] = uB;
    }
    __syncthreads();

    // ---- phase 2: per-half radix select (4x8-bit) -> exact 64th-smallest key ----
    unsigned int pref = 0;
    unsigned int need = KK;
    for (int p = 0; p < 4; ++p) {
        const int shift = 24 - 8 * p;
        if (l < 256) hist[h][l] = 0;
        __syncthreads();
        for (int j = l; j < NN; j += HALF) {
            unsigned int u = keys[h][j];
            bool active = (((u >> shift) >> 8) == pref);
            unsigned int bucket = (u >> shift) & 0xFFu;
            if (p == 0) {
                // ballot-aggregated atomics: keys' top byte has ~4 distinct
                // values (exponent concentration) -> 1 atomic per distinct
                // bucket per wave instead of 64 serialized adds.
                unsigned long long m = __ballot(active);
#pragma unroll
                for (int b = 0; b < 8; ++b) {
                    unsigned long long bb = __ballot((bucket >> b) & 1u);
                    m &= ((bucket >> b) & 1u) ? bb : ~bb;
                }
                if (active) {
                    int lane = (int)(threadIdx.x & 63);
                    int leader = __ffsll(m) - 1;
                    if (lane == leader)
                        atomicAdd(&hist[h][bucket], (unsigned int)__popcll(m));
                }
            } else {
                if (active) atomicAdd(&hist[h][bucket], 1u);
            }
        }
        __syncthreads();
        if (l == 0) {
            unsigned int cum = 0, t = 0;
            for (; t < 255; ++t) {
                if (cum + hist[h][t] >= need) break;
                cum += hist[h][t];
            }
            s_pref[h] = (pref << 8) | t;
            s_need[h] = need - cum;
        }
        __syncthreads();
        pref = s_pref[h];
        need = s_need[h];
        __syncthreads();
    }
    const unsigned int v64 = pref;

    // ---- phase 3: gather candidates (keys <= v64, superset of top-64) ----
    for (int j = l; j < NN; j += HALF) {
        unsigned int u = keys[h][j];
        if (u <= v64) {
            unsigned int pos = atomicAdd(&s_cnt[h], 1u);
            if (pos < CAND_MAX) {
                cand_idx[h][pos] = j;
                cand_key[h][pos] = u;
            }
        }
    }
    __syncthreads();
    int c = (int)s_cnt[h];
    if (c > CAND_MAX) c = CAND_MAX;

    // ---- phase 4: rank by (key asc, index asc) + write outputs ----
    const int mypid = pid[iq];
    for (int t = l; t < c; t += HALF) {
        const unsigned int kt = cand_key[h][t];
        const int jt = cand_idx[h][t];
        int rank = 0;
        for (int u = 0; u < c; ++u) {
            unsigned int ku = cand_key[h][u];
            rank += (ku < kt) || (ku == kt && cand_idx[h][u] < jt);
        }
        if (rank < KK) {
            const long e = (long)iq * KK + rank;
            out_src[e] = (float)jt;

            const float* xj = x + jt * DD;
            float diff[DD], sum[DD];
#pragma unroll
            for (int d = 0; d < DD; ++d) {
                float a = xj[d], b = xi_s[h][d];
                diff[d] = __fsub_rn(a, b);   // x_src - x_dst
                sum[d]  = __fadd_rn(a, b);   // x_src + x_dst
            }
            const float s2 = halving_sumsq16(diff);    // VALIDATED tree
            const bool m = __fsqrt_rn(s2) < 6.0f;
            out_mask[e] = m ? 1.0f : 0.0f;
            const int pj = pid[jt];
            out_y[e] = (m && pj == mypid && pj > 0) ? 1.0f : 0.0f;

            float* ef = out_ef + e * (2 * DD);
#pragma unroll
            for (int d = 0; d < DD; ++d) ef[d] = m ? diff[d] : 0.0f;
#pragma unroll
            for (int d = 0; d < DD; ++d) ef[DD + d] = m ? sum[d] : 0.0f;
        }
    }

    // dst column of edge_index
    for (int t = l; t < KK; t += HALF) {
        out_dst[(long)iq * KK + t] = (float)iq;
    }
}

extern "C" void kernel_launch(void* const* d_in, const int* in_sizes, int n_in,
                              void* d_out, int out_size, void* d_ws, size_t ws_size,
                              hipStream_t stream) {
    const float* x = (const float*)d_in[0];
    const int* pid = (const int*)d_in[1];
    float* out = (float*)d_out;

    float* out_x   = out;                                // N*D
    float* out_src = out_x + NN * DD;                    // N*K
    float* out_dst = out_src + NN * KK;                  // N*K
    float* out_y   = out_dst + NN * KK;                  // N*K
    float* out_ef  = out_y + NN * KK;                    // N*K*2D
    float* out_mask = out_ef + (long)NN * KK * 2 * DD;   // N*K

    float* sqf = (float*)d_ws;                           // 16384 f32 = 64 KB

    prep_kernel<<<NN / 256, 256, 0, stream>>>(x, out_x, sqf);
    knn_kernel<<<NN / QQ, TPB, 0, stream>>>(x, pid, sqf, out_src, out_dst,
                                            out_y, out_ef, out_mask);
}

// Round 8
// 549.741 us; speedup vs baseline: 6.2366x; 6.2366x over previous
//
#include <hip/hip_runtime.h>

#define NN 16384
#define DD 16
#define KK 64
#define QQ 4            // queries per block (share x_j loads)
#define TPB 256
#define HIST 1024       // linear buckets over d2 in [0,256), width 1/4 -> covers ALL pairs
#define CAND_MAX 256

// XLA:CPU vectorized row-reduce, minor dim 16: lane halving tree. (VALIDATED r5)
__device__ __forceinline__ float halving_sumsq16(const float* v) {
    float p[16];
#pragma unroll
    for (int d = 0; d < 16; ++d) p[d] = __fmul_rn(v[d], v[d]);
    float r8[8];
#pragma unroll
    for (int j = 0; j < 8; ++j) r8[j] = __fadd_rn(p[j], p[j + 8]);
    float r4[4];
#pragma unroll
    for (int j = 0; j < 4; ++j) r4[j] = __fadd_rn(r8[j], r8[j + 4]);
    float r2[2];
#pragma unroll
    for (int j = 0; j < 2; ++j) r2[j] = __fadd_rn(r4[j], r4[j + 2]);
    return __fadd_rn(r2[0], r2[1]);
}

// d2 recipe (VALIDATED r5): f32( f32(sqi+sqj) - 2*dot ), dot = ascending-k fmaf
__device__ __forceinline__ float d2_of(const float* xi, const float* xj,
                                       float sqi, float sqj) {
    float dot = 0.0f;
#pragma unroll
    for (int d = 0; d < DD; ++d) dot = fmaf(xi[d], xj[d], dot);
    return __fsub_rn(__fadd_rn(sqi, sqj), __fmul_rn(2.0f, dot));
}

__device__ __forceinline__ int bucket_of(float d2) {
    int b = (int)__fmul_rn(d2, 4.0f);    // monotone: [0,256) -> [0,1024)
    if (b < 0) b = 0;
    if (b >= HIST) b = HIST - 1;
    return b;
}

// ---------------- prep: f32 squared norms (halving tree) + copy x ----------------
__global__ void prep_kernel(const float* __restrict__ x,
                            float* __restrict__ out_x,
                            float* __restrict__ sqf) {
    int i = blockIdx.x * blockDim.x + threadIdx.x;
    if (i < NN) {
        float v[DD];
#pragma unroll
        for (int d = 0; d < DD; ++d) v[d] = x[i * DD + d];
        sqf[i] = halving_sumsq16(v);
    }
    for (int t = i; t < NN * DD; t += gridDim.x * blockDim.x) {
        out_x[t] = x[t];
    }
}

// ---------------- main: 4 queries/block, full-hist select, two scans ----------------
__global__ __launch_bounds__(TPB) void knn_kernel(
        const float* __restrict__ x,
        const int* __restrict__ pid,
        const float* __restrict__ sqf,
        float* __restrict__ out_src,
        float* __restrict__ out_dst,
        float* __restrict__ out_y,
        float* __restrict__ out_ef,
        float* __restrict__ out_mask) {
    __shared__ unsigned int hist[QQ][HIST];          // 16 KB
    __shared__ unsigned int cand_key[QQ][CAND_MAX];  // 4 KB
    __shared__ int cand_idx[QQ][CAND_MAX];           // 4 KB
    __shared__ unsigned int wavesum[QQ][TPB / 64];
    __shared__ int s_bsel[QQ];
    __shared__ unsigned int s_candcnt[QQ];

    const int bid = blockIdx.x;
    const int tid = threadIdx.x;
    const int lane = tid & 63;
    const int w = tid >> 6;
    const int iA = bid * QQ;

    // init LDS
    for (int t = tid; t < QQ * HIST; t += TPB)
        ((unsigned int*)hist)[t] = 0;
    if (tid < QQ) s_candcnt[tid] = 0;

    // query vectors + norms in registers
    float xq[QQ][DD];
    float sq[QQ];
#pragma unroll
    for (int q = 0; q < QQ; ++q) {
        const float4* p = reinterpret_cast<const float4*>(x + (iA + q) * DD);
        float4 a0 = p[0], a1 = p[1], a2 = p[2], a3 = p[3];
        xq[q][0]=a0.x; xq[q][1]=a0.y; xq[q][2]=a0.z; xq[q][3]=a0.w;
        xq[q][4]=a1.x; xq[q][5]=a1.y; xq[q][6]=a1.z; xq[q][7]=a1.w;
        xq[q][8]=a2.x; xq[q][9]=a2.y; xq[q][10]=a2.z; xq[q][11]=a2.w;
        xq[q][12]=a3.x; xq[q][13]=a3.y; xq[q][14]=a3.z; xq[q][15]=a3.w;
        sq[q] = sqf[iA + q];
    }
    __syncthreads();

    // ---- scan 1: histogram ALL non-self points (hist always holds 16383 keys) ----
    for (int j = tid; j < NN; j += TPB) {
        const float4* xj4 = reinterpret_cast<const float4*>(x + j * DD);
        float4 a0 = xj4[0], a1 = xj4[1], a2 = xj4[2], a3 = xj4[3];
        float xj[DD] = {a0.x, a0.y, a0.z, a0.w, a1.x, a1.y, a1.z, a1.w,
                        a2.x, a2.y, a2.z, a2.w, a3.x, a3.y, a3.z, a3.w};
        const float sj = sqf[j];
#pragma unroll
        for (int q = 0; q < QQ; ++q) {
            float d2 = d2_of(xq[q], xj, sq[q], sj);
            if (j != iA + q)
                atomicAdd(&hist[q][bucket_of(d2)], 1u);
        }
    }
    __syncthreads();

    // ---- phase 2: parallel prefix-scan over buckets -> bucket of 64th key ----
    {
        unsigned int local[QQ], inc[QQ];
#pragma unroll
        for (int q = 0; q < QQ; ++q) {
            const int b0 = tid * (HIST / TPB);         // 4 buckets per thread
            unsigned int s = 0;
#pragma unroll
            for (int b = 0; b < HIST / TPB; ++b) s += hist[q][b0 + b];
            local[q] = s;
            unsigned int v = s;
#pragma unroll
            for (int off = 1; off < 64; off <<= 1) {
                unsigned int n = __shfl_up(v, off, 64);
                if (lane >= off) v += n;
            }
            inc[q] = v;
        }
        if (lane == 63)
#pragma unroll
            for (int q = 0; q < QQ; ++q) wavesum[q][w] = inc[q];
        __syncthreads();
#pragma unroll
        for (int q = 0; q < QQ; ++q) {
            unsigned int woff = 0;
            for (int ww = 0; ww < w; ++ww) woff += wavesum[q][ww];
            unsigned int cum = inc[q] + woff;          // count in buckets [0, 4t+4)
            unsigned int prev = cum - local[q];        // count in buckets [0, 4t)
            if (prev < KK && KK <= cum) {              // unique thread
                unsigned int acc = prev;
                int b = tid * (HIST / TPB);
                while (acc + hist[q][b] < KK) { acc += hist[q][b]; ++b; }
                s_bsel[q] = b;
            }
        }
    }
    __syncthreads();

    // ---- scan 2: gather candidates (bucket <= bsel), bit-identical d2 ----
    for (int j = tid; j < NN; j += TPB) {
        const float4* xj4 = reinterpret_cast<const float4*>(x + j * DD);
        float4 a0 = xj4[0], a1 = xj4[1], a2 = xj4[2], a3 = xj4[3];
        float xj[DD] = {a0.x, a0.y, a0.z, a0.w, a1.x, a1.y, a1.z, a1.w,
                        a2.x, a2.y, a2.z, a2.w, a3.x, a3.y, a3.z, a3.w};
        const float sj = sqf[j];
#pragma unroll
        for (int q = 0; q < QQ; ++q) {
            float d2 = d2_of(xq[q], xj, sq[q], sj);
            if (j != iA + q && bucket_of(d2) <= s_bsel[q]) {
                unsigned int pos = atomicAdd(&s_candcnt[q], 1u);
                if (pos < CAND_MAX) {
                    unsigned int u = __float_as_uint(d2);
                    u ^= (u & 0x80000000u) ? 0xFFFFFFFFu : 0x80000000u;
                    cand_key[q][pos] = u;
                    cand_idx[q][pos] = j;
                }
            }
        }
    }
    __syncthreads();

    // ---- phase 4: rank by (key asc, index asc) + write outputs (VALIDATED r5/r6) ----
    for (int q = 0; q < QQ; ++q) {
        const int iq = iA + q;
        const int mypid = pid[iq];
        int c = (int)s_candcnt[q];
        if (c > CAND_MAX) c = CAND_MAX;
        for (int t = tid; t < c; t += TPB) {
            const unsigned int kt = cand_key[q][t];
            const int jt = cand_idx[q][t];
            int rank = 0;
            for (int u = 0; u < c; ++u) {
                unsigned int ku = cand_key[q][u];
                rank += (ku < kt) || (ku == kt && cand_idx[q][u] < jt);
            }
            if (rank < KK) {
                const long e = (long)iq * KK + rank;
                out_src[e] = (float)jt;

                const float* xj = x + jt * DD;
                float diff[DD], sum[DD];
#pragma unroll
                for (int d = 0; d < DD; ++d) {
                    float a = xj[d], b = xq[q][d];
                    diff[d] = __fsub_rn(a, b);   // x_src - x_dst
                    sum[d]  = __fadd_rn(a, b);   // x_src + x_dst
                }
                const float s2 = halving_sumsq16(diff);    // VALIDATED tree
                const bool m = __fsqrt_rn(s2) < 6.0f;
                out_mask[e] = m ? 1.0f : 0.0f;
                const int pj = pid[jt];
                out_y[e] = (m && pj == mypid && pj > 0) ? 1.0f : 0.0f;

                float* ef = out_ef + e * (2 * DD);
#pragma unroll
                for (int d = 0; d < DD; ++d) ef[d] = m ? diff[d] : 0.0f;
#pragma unroll
                for (int d = 0; d < DD; ++d) ef[DD + d] = m ? sum[d] : 0.0f;
            }
        }
    }

    // dst column of edge_index
    for (int t = tid; t < QQ * KK; t += TPB) {
        out_dst[(long)iA * KK + t] = (float)(iA + t / KK);
    }
}

extern "C" void kernel_launch(void* const* d_in, const int* in_sizes, int n_in,
                              void* d_out, int out_size, void* d_ws, size_t ws_size,
                              hipStream_t stream) {
    const float* x = (const float*)d_in[0];
    const int* pid = (const int*)d_in[1];
    float* out = (float*)d_out;

    float* out_x   = out;                                // N*D
    float* out_src = out_x + NN * DD;                    // N*K
    float* out_dst = out_src + NN * KK;                  // N*K
    float* out_y   = out_dst + NN * KK;                  // N*K
    float* out_ef  = out_y + NN * KK;                    // N*K*2D
    float* out_mask = out_ef + (long)NN * KK * 2 * DD;   // N*K

    float* sqf = (float*)d_ws;                           // 16384 f32 = 64 KB

    prep_kernel<<<NN / 256, 256, 0, stream>>>(x, out_x, sqf);
    knn_kernel<<<NN / QQ, TPB, 0, stream>>>(x, pid, sqf, out_src, out_dst,
                                            out_y, out_ef, out_mask);
}

// Round 9
// 402.713 us; speedup vs baseline: 8.5136x; 1.3651x over previous
//
#include <hip/hip_runtime.h>

#define NN 16384
#define DD 16
#define KK 64
#define QQ 4            // queries per block (share x_j loads)
#define TPB 256
#define HIST 1024       // buckets over d2 in [0,256), width 1/4 (fallback-compatible)
#define LIST_MAX 896    // expected ~600 entries at 3.6% target, >10 sigma margin
#define CAND_MAX 256

// XLA:CPU vectorized row-reduce, minor dim 16: lane halving tree. (VALIDATED r5)
__device__ __forceinline__ float halving_sumsq16(const float* v) {
    float p[16];
#pragma unroll
    for (int d = 0; d < 16; ++d) p[d] = __fmul_rn(v[d], v[d]);
    float r8[8];
#pragma unroll
    for (int j = 0; j < 8; ++j) r8[j] = __fadd_rn(p[j], p[j + 8]);
    float r4[4];
#pragma unroll
    for (int j = 0; j < 4; ++j) r4[j] = __fadd_rn(r8[j], r8[j + 4]);
    float r2[2];
#pragma unroll
    for (int j = 0; j < 2; ++j) r2[j] = __fadd_rn(r4[j], r4[j + 2]);
    return __fadd_rn(r2[0], r2[1]);
}

// d2 recipe (VALIDATED r5): f32( f32(sqi+sqj) - 2*dot ), dot = ascending-k fmaf
__device__ __forceinline__ float d2_of(const float* xi, const float* xj,
                                       float sqi, float sqj) {
    float dot = 0.0f;
#pragma unroll
    for (int d = 0; d < DD; ++d) dot = fmaf(xi[d], xj[d], dot);
    return __fsub_rn(__fadd_rn(sqi, sqj), __fmul_rn(2.0f, dot));
}

__device__ __forceinline__ int bucket_of(float d2) {   // fallback path (r8-validated)
    int b = (int)__fmul_rn(d2, 4.0f);
    if (b < 0) b = 0;
    if (b >= HIST) b = HIST - 1;
    return b;
}

// ---------------- prep: f32 squared norms (halving tree) + copy x ----------------
__global__ void prep_kernel(const float* __restrict__ x,
                            float* __restrict__ out_x,
                            float* __restrict__ sqf) {
    int i = blockIdx.x * blockDim.x + threadIdx.x;
    if (i < NN) {
        float v[DD];
#pragma unroll
        for (int d = 0; d < DD; ++d) v[d] = x[i * DD + d];
        sqf[i] = halving_sumsq16(v);
    }
    for (int t = i; t < NN * DD; t += gridDim.x * blockDim.x) {
        out_x[t] = x[t];
    }
}

// ---------------- main: 4 queries/block, single scan + adaptive list ----------------
__global__ __launch_bounds__(TPB) void knn_kernel(
        const float* __restrict__ x,
        const int* __restrict__ pid,
        const float* __restrict__ sqf,
        float* __restrict__ out_src,
        float* __restrict__ out_dst,
        float* __restrict__ out_y,
        float* __restrict__ out_ef,
        float* __restrict__ out_mask) {
    __shared__ unsigned int hist[QQ][HIST];          // 16 KB
    __shared__ unsigned int list[QQ][LIST_MAX];      // 14 KB  (qd2<<16 | j)
    __shared__ unsigned int cand_key[QQ][CAND_MAX];  // 4 KB
    __shared__ int cand_idx[QQ][CAND_MAX];           // 4 KB
    __shared__ unsigned int wavesum[QQ][TPB / 64];
    __shared__ int s_bsel[QQ];
    __shared__ unsigned int s_listcnt[QQ], s_candcnt[QQ];
    __shared__ int s_fb[QQ];

    const int bid = blockIdx.x;
    const int tid = threadIdx.x;
    const int lane = tid & 63;
    const int w = tid >> 6;
    const int iA = bid * QQ;

    // ---- A: init ----
    for (int t = tid; t < QQ * HIST; t += TPB)
        ((unsigned int*)hist)[t] = 0;
    if (tid < QQ) { s_listcnt[tid] = 0; s_candcnt[tid] = 0; s_bsel[tid] = HIST - 1; }

    float xq[QQ][DD];
    float sq[QQ], Tq[QQ];
#pragma unroll
    for (int q = 0; q < QQ; ++q) {
        const float4* p = reinterpret_cast<const float4*>(x + (iA + q) * DD);
        float4 a0 = p[0], a1 = p[1], a2 = p[2], a3 = p[3];
        xq[q][0]=a0.x; xq[q][1]=a0.y; xq[q][2]=a0.z; xq[q][3]=a0.w;
        xq[q][4]=a1.x; xq[q][5]=a1.y; xq[q][6]=a1.z; xq[q][7]=a1.w;
        xq[q][8]=a2.x; xq[q][9]=a2.y; xq[q][10]=a2.z; xq[q][11]=a2.w;
        xq[q][12]=a3.x; xq[q][13]=a3.y; xq[q][14]=a3.z; xq[q][15]=a3.w;
        sq[q] = sqf[iA + q];
        // adaptive cut: ~3.6% quantile of noncentral chi2_16(r^2) (Gaussian approx)
        Tq[q] = 16.0f + sq[q] - 1.8f * sqrtf(32.0f + 4.0f * sq[q]);
    }
    __syncthreads();

    // ---- B: single scan; sub-threshold points -> packed list ----
    for (int j = tid; j < NN; j += TPB) {
        const float4* xj4 = reinterpret_cast<const float4*>(x + j * DD);
        float4 a0 = xj4[0], a1 = xj4[1], a2 = xj4[2], a3 = xj4[3];
        float xj[DD] = {a0.x, a0.y, a0.z, a0.w, a1.x, a1.y, a1.z, a1.w,
                        a2.x, a2.y, a2.z, a2.w, a3.x, a3.y, a3.z, a3.w};
        const float sj = sqf[j];
#pragma unroll
        for (int q = 0; q < QQ; ++q) {
            float d2 = d2_of(xq[q], xj, sq[q], sj);
            if (d2 < Tq[q] && j != iA + q) {
                int qd2 = (int)__fmul_rn(d2, 256.0f);
                if (qd2 < 0) qd2 = 0;
                if (qd2 > 65535) qd2 = 65535;
                unsigned int pos = atomicAdd(&s_listcnt[q], 1u);
                if (pos < LIST_MAX)
                    list[q][pos] = ((unsigned int)qd2 << 16) | (unsigned int)j;
            }
        }
    }
    __syncthreads();

    // ---- C: flags ----
    if (tid < QQ)
        s_fb[tid] = (s_listcnt[tid] < KK) || (s_listcnt[tid] > LIST_MAX);
    __syncthreads();
    const int anyfb = s_fb[0] | s_fb[1] | s_fb[2] | s_fb[3];

    // ---- D: (rare) fallback rescan: full-range hist for flagged queries ----
    if (anyfb) {
        for (int j = tid; j < NN; j += TPB) {
            const float4* xj4 = reinterpret_cast<const float4*>(x + j * DD);
            float4 a0 = xj4[0], a1 = xj4[1], a2 = xj4[2], a3 = xj4[3];
            float xj[DD] = {a0.x, a0.y, a0.z, a0.w, a1.x, a1.y, a1.z, a1.w,
                            a2.x, a2.y, a2.z, a2.w, a3.x, a3.y, a3.z, a3.w};
            const float sj = sqf[j];
#pragma unroll
            for (int q = 0; q < QQ; ++q) {
                if (s_fb[q] && j != iA + q) {
                    float d2 = d2_of(xq[q], xj, sq[q], sj);
                    atomicAdd(&hist[q][bucket_of(d2)], 1u);
                }
            }
        }
    }

    // ---- E: fast-path hist from list entries (qd2>>6 == 1/4-wide buckets) ----
#pragma unroll
    for (int q = 0; q < QQ; ++q) {
        if (!s_fb[q]) {
            const int lc = (int)s_listcnt[q];
            for (int e = tid; e < lc; e += TPB)
                atomicAdd(&hist[q][list[q][e] >> 22], 1u);
        }
    }
    __syncthreads();

    // ---- F: prefix-scan over buckets -> bucket of the 64th key (r8-validated) ----
    {
        unsigned int local[QQ], inc[QQ];
#pragma unroll
        for (int q = 0; q < QQ; ++q) {
            const int b0 = tid * (HIST / TPB);
            unsigned int s = 0;
#pragma unroll
            for (int b = 0; b < HIST / TPB; ++b) s += hist[q][b0 + b];
            local[q] = s;
            unsigned int v = s;
#pragma unroll
            for (int off = 1; off < 64; off <<= 1) {
                unsigned int n = __shfl_up(v, off, 64);
                if (lane >= off) v += n;
            }
            inc[q] = v;
        }
        if (lane == 63)
#pragma unroll
            for (int q = 0; q < QQ; ++q) wavesum[q][w] = inc[q];
        __syncthreads();
#pragma unroll
        for (int q = 0; q < QQ; ++q) {
            unsigned int woff = 0;
            for (int ww = 0; ww < w; ++ww) woff += wavesum[q][ww];
            unsigned int cum = inc[q] + woff;
            unsigned int prev = cum - local[q];
            if (prev < KK && KK <= cum) {
                unsigned int acc = prev;
                int b = tid * (HIST / TPB);
                while (acc + hist[q][b] < KK) { acc += hist[q][b]; ++b; }
                s_bsel[q] = b;
            }
        }
    }
    __syncthreads();

    // ---- G: candidate gather ----
    // fast path: from list (bucket <= bsel), recompute exact d2 (bit-identical)
#pragma unroll
    for (int q = 0; q < QQ; ++q) {
        if (!s_fb[q]) {
            const int bsel = s_bsel[q];
            const int lc = (int)s_listcnt[q];
            for (int e = tid; e < lc; e += TPB) {
                const unsigned int entry = list[q][e];
                if ((int)(entry >> 22) <= bsel) {
                    const int j = (int)(entry & 0xFFFFu);
                    const float4* xj4 = reinterpret_cast<const float4*>(x + j * DD);
                    float4 a0 = xj4[0], a1 = xj4[1], a2 = xj4[2], a3 = xj4[3];
                    float xj[DD] = {a0.x, a0.y, a0.z, a0.w, a1.x, a1.y, a1.z, a1.w,
                                    a2.x, a2.y, a2.z, a2.w, a3.x, a3.y, a3.z, a3.w};
                    float d2 = d2_of(xq[q], xj, sq[q], sqf[j]);
                    unsigned int pos = atomicAdd(&s_candcnt[q], 1u);
                    if (pos < CAND_MAX) {
                        unsigned int u = __float_as_uint(d2);
                        u ^= (u & 0x80000000u) ? 0xFFFFFFFFu : 0x80000000u;
                        cand_key[q][pos] = u;
                        cand_idx[q][pos] = j;
                    }
                }
            }
        }
    }
    // fallback: full scan (r8-validated semantics)
    if (anyfb) {
        for (int j = tid; j < NN; j += TPB) {
            const float4* xj4 = reinterpret_cast<const float4*>(x + j * DD);
            float4 a0 = xj4[0], a1 = xj4[1], a2 = xj4[2], a3 = xj4[3];
            float xj[DD] = {a0.x, a0.y, a0.z, a0.w, a1.x, a1.y, a1.z, a1.w,
                            a2.x, a2.y, a2.z, a2.w, a3.x, a3.y, a3.z, a3.w};
            const float sj = sqf[j];
#pragma unroll
            for (int q = 0; q < QQ; ++q) {
                if (s_fb[q] && j != iA + q) {
                    float d2 = d2_of(xq[q], xj, sq[q], sj);
                    if (bucket_of(d2) <= s_bsel[q]) {
                        unsigned int pos = atomicAdd(&s_candcnt[q], 1u);
                        if (pos < CAND_MAX) {
                            unsigned int u = __float_as_uint(d2);
                            u ^= (u & 0x80000000u) ? 0xFFFFFFFFu : 0x80000000u;
                            cand_key[q][pos] = u;
                            cand_idx[q][pos] = j;
                        }
                    }
                }
            }
        }
    }
    __syncthreads();

    // ---- H: rank by (key asc, index asc) + write outputs (VALIDATED) ----
    for (int q = 0; q < QQ; ++q) {
        const int iq = iA + q;
        const int mypid = pid[iq];
        int c = (int)s_candcnt[q];
        if (c > CAND_MAX) c = CAND_MAX;
        for (int t = tid; t < c; t += TPB) {
            const unsigned int kt = cand_key[q][t];
            const int jt = cand_idx[q][t];
            int rank = 0;
            for (int u = 0; u < c; ++u) {
                unsigned int ku = cand_key[q][u];
                rank += (ku < kt) || (ku == kt && cand_idx[q][u] < jt);
            }
            if (rank < KK) {
                const long e = (long)iq * KK + rank;
                out_src[e] = (float)jt;

                const float* xj = x + jt * DD;
                float diff[DD], sum[DD];
#pragma unroll
                for (int d = 0; d < DD; ++d) {
                    float a = xj[d], b = xq[q][d];
                    diff[d] = __fsub_rn(a, b);   // x_src - x_dst
                    sum[d]  = __fadd_rn(a, b);   // x_src + x_dst
                }
                const float s2 = halving_sumsq16(diff);    // VALIDATED tree
                const bool m = __fsqrt_rn(s2) < 6.0f;
                out_mask[e] = m ? 1.0f : 0.0f;
                const int pj = pid[jt];
                out_y[e] = (m && pj == mypid && pj > 0) ? 1.0f : 0.0f;

                float* ef = out_ef + e * (2 * DD);
#pragma unroll
                for (int d = 0; d < DD; ++d) ef[d] = m ? diff[d] : 0.0f;
#pragma unroll
                for (int d = 0; d < DD; ++d) ef[DD + d] = m ? sum[d] : 0.0f;
            }
        }
    }

    // dst column of edge_index
    for (int t = tid; t < QQ * KK; t += TPB) {
        out_dst[(long)iA * KK + t] = (float)(iA + t / KK);
    }
}

extern "C" void kernel_launch(void* const* d_in, const int* in_sizes, int n_in,
                              void* d_out, int out_size, void* d_ws, size_t ws_size,
                              hipStream_t stream) {
    const float* x = (const float*)d_in[0];
    const int* pid = (const int*)d_in[1];
    float* out = (float*)d_out;

    float* out_x   = out;                                // N*D
    float* out_src = out_x + NN * DD;                    // N*K
    float* out_dst = out_src + NN * KK;                  // N*K
    float* out_y   = out_dst + NN * KK;                  // N*K
    float* out_ef  = out_y + NN * KK;                    // N*K*2D
    float* out_mask = out_ef + (long)NN * KK * 2 * DD;   // N*K

    float* sqf = (float*)d_ws;                           // 16384 f32 = 64 KB

    prep_kernel<<<NN / 256, 256, 0, stream>>>(x, out_x, sqf);
    knn_kernel<<<NN / QQ, TPB, 0, stream>>>(x, pid, sqf, out_src, out_dst,
                                            out_y, out_ef, out_mask);
}